// Round 1
// baseline (514.154 us; speedup 1.0000x reference)
//
#include <hip/hip_runtime.h>
#include <hip/hip_bf16.h>

#define SEQ 4096
#define EMB 1024
#define NHD 16
#define HDD 64

using bf16 = __hip_bfloat16;
using bf16x8 = __attribute__((ext_vector_type(8))) short;
using f32x4  = __attribute__((ext_vector_type(4))) float;

#define MFMA16(a, b, c) __builtin_amdgcn_mfma_f32_16x16x32_bf16((a), (b), (c), 0, 0, 0)

__device__ __forceinline__ float b2f(bf16 b) { return __bfloat162float(b); }

// ---------------- prep: split f32 -> hi/lo bf16 ----------------
__global__ void split_kernel(const float* __restrict__ src, bf16* __restrict__ hi,
                             bf16* __restrict__ lo, int n4) {
    int i = blockIdx.x * blockDim.x + threadIdx.x;
    if (i >= n4) return;
    float4 v = ((const float4*)src)[i];
    float vv[4] = {v.x, v.y, v.z, v.w};
#pragma unroll
    for (int j = 0; j < 4; j++) {
        bf16 h = __float2bfloat16(vv[j]);
        hi[i * 4 + j] = h;
        lo[i * 4 + j] = __float2bfloat16(vv[j] - b2f(h));
    }
}

// ---------------- prep: W[k][n] f32 -> Wt[n][k] hi/lo bf16 ----------------
__global__ void wtrans_kernel(const float* __restrict__ W, bf16* __restrict__ wth,
                              bf16* __restrict__ wtl) {
    __shared__ float tile[32][33];
    int n0 = blockIdx.x * 32, k0 = blockIdx.y * 32;
    int tx = threadIdx.x, ty = threadIdx.y;
    for (int r = ty; r < 32; r += 8)
        tile[r][tx] = W[(k0 + r) * EMB + n0 + tx];
    __syncthreads();
    for (int r = ty; r < 32; r += 8) {
        float v = tile[tx][r];  // = W[k0+tx][n0+r]
        bf16 h = __float2bfloat16(v);
        wth[(n0 + r) * EMB + k0 + tx] = h;
        wtl[(n0 + r) * EMB + k0 + tx] = __float2bfloat16(v - b2f(h));
    }
}

// ---------------- projection GEMM: C = A @ B (split bf16, fp32 acc) -------
// A given as hi/lo [M][K]; B given TRANSPOSED hi/lo [N][K]. Output hi/lo bf16.
template <int NTERMS>
__global__ __launch_bounds__(256) void proj_gemm(
    const bf16* __restrict__ Ah, const bf16* __restrict__ Al,
    const bf16* __restrict__ Bth, const bf16* __restrict__ Btl,
    bf16* __restrict__ Chi, bf16* __restrict__ Clo, float scale) {
    // LDS tiles, row stride 40 elems (80B, 16B-aligned, conflict-mild)
    __shared__ __align__(16) bf16 lAh[128 * 40];
    __shared__ __align__(16) bf16 lAl[128 * 40];
    __shared__ __align__(16) bf16 lBh[128 * 40];
    __shared__ __align__(16) bf16 lBl[128 * 40];
    const int t = threadIdx.x;
    const int m0 = blockIdx.y * 128, n0 = blockIdx.x * 128;
    const int wid = t >> 6, lane = t & 63, lr = lane & 15, lg = lane >> 4;
    const int wr = (wid >> 1) * 64, wc = (wid & 1) * 64;

    f32x4 acc[4][4];
#pragma unroll
    for (int i = 0; i < 4; i++)
#pragma unroll
        for (int j = 0; j < 4; j++) acc[i][j] = (f32x4){0.f, 0.f, 0.f, 0.f};

    for (int k0 = 0; k0 < EMB; k0 += 32) {
#pragma unroll
        for (int c = t; c < 512; c += 256) {
            int row = c >> 2, slot = c & 3;  // 4x 16B chunks per 32-elem row
            *(uint4*)&lAh[row * 40 + slot * 8] =
                *(const uint4*)&Ah[(m0 + row) * EMB + k0 + slot * 8];
            *(uint4*)&lBh[row * 40 + slot * 8] =
                *(const uint4*)&Bth[(n0 + row) * EMB + k0 + slot * 8];
            if constexpr (NTERMS == 3) {
                *(uint4*)&lAl[row * 40 + slot * 8] =
                    *(const uint4*)&Al[(m0 + row) * EMB + k0 + slot * 8];
                *(uint4*)&lBl[row * 40 + slot * 8] =
                    *(const uint4*)&Btl[(n0 + row) * EMB + k0 + slot * 8];
            }
        }
        __syncthreads();
        bf16x8 fah[4], fbh[4], fal[4], fbl[4];
#pragma unroll
        for (int i = 0; i < 4; i++) {
            fah[i] = *(const bf16x8*)&lAh[(wr + i * 16 + lr) * 40 + lg * 8];
            fbh[i] = *(const bf16x8*)&lBh[(wc + i * 16 + lr) * 40 + lg * 8];
            if constexpr (NTERMS == 3) {
                fal[i] = *(const bf16x8*)&lAl[(wr + i * 16 + lr) * 40 + lg * 8];
                fbl[i] = *(const bf16x8*)&lBl[(wc + i * 16 + lr) * 40 + lg * 8];
            }
        }
#pragma unroll
        for (int i = 0; i < 4; i++)
#pragma unroll
            for (int j = 0; j < 4; j++) {
                acc[i][j] = MFMA16(fah[i], fbh[j], acc[i][j]);
                if constexpr (NTERMS == 3) {
                    acc[i][j] = MFMA16(fah[i], fbl[j], acc[i][j]);
                    acc[i][j] = MFMA16(fal[i], fbh[j], acc[i][j]);
                }
            }
        __syncthreads();
    }
#pragma unroll
    for (int i = 0; i < 4; i++)
#pragma unroll
        for (int j = 0; j < 4; j++)
#pragma unroll
            for (int q = 0; q < 4; q++) {
                float cv = acc[i][j][q] * scale;
                int m = m0 + wr + i * 16 + lg * 4 + q;
                int n = n0 + wc + j * 16 + lr;
                bf16 h = __float2bfloat16(cv);
                Chi[m * EMB + n] = h;
                if (Clo != nullptr)
                    Clo[m * EMB + n] = __float2bfloat16(cv - b2f(h));
            }
}

// ---------------- V transpose per head: vh[S][E] -> vt[H][D][S] ----------
__global__ void vtrans_kernel(const bf16* __restrict__ vh, bf16* __restrict__ vt) {
    __shared__ bf16 tile[64][65];
    int s0 = blockIdx.x * 64;
    int h = blockIdx.y;
    int tx = threadIdx.x, ty = threadIdx.y;  // (64,4)
    for (int r = ty; r < 64; r += 4)
        tile[r][tx] = vh[(s0 + r) * EMB + h * HDD + tx];
    __syncthreads();
    for (int r = ty; r < 64; r += 4)
        vt[(h * HDD + r) * SEQ + s0 + tx] = tile[tx][r];
}

// ---------------- fused flash attention ----------------
// grid: (SEQ/64, NHD). 256 thr = 4 waves, each wave owns 16 q-rows.
__global__ __launch_bounds__(256) void attn_kernel(
    const bf16* __restrict__ qh, const bf16* __restrict__ ql,
    const bf16* __restrict__ kh, const bf16* __restrict__ kl,
    const bf16* __restrict__ vt, float* __restrict__ out) {
    // row stride 72 elems (144B, 16B-aligned)
    __shared__ __align__(16) bf16 lQh[64 * 72], lQl[64 * 72];
    __shared__ __align__(16) bf16 lKh[64 * 72], lKl[64 * 72];
    __shared__ __align__(16) bf16 lV[64 * 72];
    __shared__ __align__(16) bf16 lP[4][16 * 72];
    const int t = threadIdx.x;
    const int q0 = blockIdx.x * 64;
    const int h = blockIdx.y;
    const int wid = t >> 6, lane = t & 63, lr = lane & 15, lg = lane >> 4;
    const int wq = wid * 16;

    // stage Q block (hi & lo)
#pragma unroll
    for (int c = t; c < 512; c += 256) {
        int row = c >> 3, slot = c & 7;  // 8x 16B chunks per 64-elem row
        *(uint4*)&lQh[row * 72 + slot * 8] =
            *(const uint4*)&qh[(q0 + row) * EMB + h * HDD + slot * 8];
        *(uint4*)&lQl[row * 72 + slot * 8] =
            *(const uint4*)&ql[(q0 + row) * EMB + h * HDD + slot * 8];
    }
    __syncthreads();

    // hoist Q fragments (A-operand: row = lane&15, k = half*32 + lg*8 + i)
    bf16x8 fqh[2], fql[2];
#pragma unroll
    for (int hf = 0; hf < 2; hf++) {
        fqh[hf] = *(const bf16x8*)&lQh[(wq + lr) * 72 + hf * 32 + lg * 8];
        fql[hf] = *(const bf16x8*)&lQl[(wq + lr) * 72 + hf * 32 + lg * 8];
    }

    f32x4 Ofr[4];
#pragma unroll
    for (int d = 0; d < 4; d++) Ofr[d] = (f32x4){0.f, 0.f, 0.f, 0.f};
    float Mr[4] = {-1e30f, -1e30f, -1e30f, -1e30f};
    float Lr[4] = {0.f, 0.f, 0.f, 0.f};

    for (int s0 = 0; s0 < SEQ; s0 += 64) {
        __syncthreads();  // previous tile's compute done before restage
#pragma unroll
        for (int c = t; c < 512; c += 256) {
            int row = c >> 3, slot = c & 7;
            *(uint4*)&lKh[row * 72 + slot * 8] =
                *(const uint4*)&kh[(s0 + row) * EMB + h * HDD + slot * 8];
            *(uint4*)&lKl[row * 72 + slot * 8] =
                *(const uint4*)&kl[(s0 + row) * EMB + h * HDD + slot * 8];
            *(uint4*)&lV[row * 72 + slot * 8] =
                *(const uint4*)&vt[(h * HDD + row) * SEQ + s0 + slot * 8];
        }
        __syncthreads();

        // S = Q K^T (scale pre-folded into Q). 3-term split, fp32 acc.
        f32x4 sfr[4];
#pragma unroll
        for (int kc = 0; kc < 4; kc++) {
            f32x4 a = (f32x4){0.f, 0.f, 0.f, 0.f};
#pragma unroll
            for (int hf = 0; hf < 2; hf++) {
                bf16x8 kbh = *(const bf16x8*)&lKh[(kc * 16 + lr) * 72 + hf * 32 + lg * 8];
                bf16x8 kbl = *(const bf16x8*)&lKl[(kc * 16 + lr) * 72 + hf * 32 + lg * 8];
                a = MFMA16(fqh[hf], kbh, a);
                a = MFMA16(fqh[hf], kbl, a);
                a = MFMA16(fql[hf], kbh, a);
            }
            sfr[kc] = a;
        }

        // online softmax: row m = lg*4+j lives in 16-lane group (xor 1,2,4,8)
        float mt[4];
#pragma unroll
        for (int j = 0; j < 4; j++)
            mt[j] = fmaxf(fmaxf(sfr[0][j], sfr[1][j]), fmaxf(sfr[2][j], sfr[3][j]));
#pragma unroll
        for (int off = 1; off < 16; off <<= 1)
#pragma unroll
            for (int j = 0; j < 4; j++) mt[j] = fmaxf(mt[j], __shfl_xor(mt[j], off));

        float fac[4], ps[4];
#pragma unroll
        for (int j = 0; j < 4; j++) {
            float mn = fmaxf(Mr[j], mt[j]);
            fac[j] = exp2f((Mr[j] - mn) * 1.44269504f);
            Mr[j] = mn;
            ps[j] = 0.f;
        }
#pragma unroll
        for (int kc = 0; kc < 4; kc++)
#pragma unroll
            for (int j = 0; j < 4; j++) {
                float p = exp2f((sfr[kc][j] - Mr[j]) * 1.44269504f);
                sfr[kc][j] = p;
                ps[j] += p;
            }
#pragma unroll
        for (int off = 1; off < 16; off <<= 1)
#pragma unroll
            for (int j = 0; j < 4; j++) ps[j] += __shfl_xor(ps[j], off);
#pragma unroll
        for (int j = 0; j < 4; j++) Lr[j] = Lr[j] * fac[j] + ps[j];
#pragma unroll
        for (int d = 0; d < 4; d++)
#pragma unroll
            for (int j = 0; j < 4; j++) Ofr[d][j] *= fac[j];

        // P -> LDS (per-wave region; same-wave RAW, compiler inserts lgkmcnt)
#pragma unroll
        for (int kc = 0; kc < 4; kc++)
#pragma unroll
            for (int j = 0; j < 4; j++)
                lP[wid][(lg * 4 + j) * 72 + kc * 16 + lr] = __float2bfloat16(sfr[kc][j]);

        // O += P @ V  (V staged transposed: lV[d][k])
#pragma unroll
        for (int ks = 0; ks < 2; ks++) {
            bf16x8 pf = *(const bf16x8*)&lP[wid][lr * 72 + ks * 32 + lg * 8];
#pragma unroll
            for (int df = 0; df < 4; df++) {
                bf16x8 vf = *(const bf16x8*)&lV[(df * 16 + lr) * 72 + ks * 32 + lg * 8];
                Ofr[df] = MFMA16(pf, vf, Ofr[df]);
            }
        }
    }

    // epilogue: out[q0+wq+m][h*64 + df*16 + lr] = O/L
#pragma unroll
    for (int df = 0; df < 4; df++)
#pragma unroll
        for (int j = 0; j < 4; j++) {
            int srow = q0 + wq + lg * 4 + j;
            int col = h * HDD + df * 16 + lr;
            out[srow * EMB + col] = Ofr[df][j] / Lr[j];
        }
}

// ---------------- launch ----------------
extern "C" void kernel_launch(void* const* d_in, const int* in_sizes, int n_in,
                              void* d_out, int out_size, void* d_ws, size_t ws_size,
                              hipStream_t stream) {
    const float* x = (const float*)d_in[0];
    const float* Wq = (const float*)d_in[1];
    const float* Wk = (const float*)d_in[2];
    const float* Wv = (const float*)d_in[3];
    float* out = (float*)d_out;

    char* ws = (char*)d_ws;
    size_t off = 0;
    auto alloc = [&](size_t elems) -> bf16* {
        bf16* p = (bf16*)(ws + off);
        off += elems * sizeof(bf16);
        return p;
    };
    bf16* xh = alloc((size_t)SEQ * EMB);
    bf16* xl = alloc((size_t)SEQ * EMB);
    bf16* wthq = alloc((size_t)EMB * EMB);
    bf16* wtlq = alloc((size_t)EMB * EMB);
    bf16* wthk = alloc((size_t)EMB * EMB);
    bf16* wtlk = alloc((size_t)EMB * EMB);
    bf16* wthv = alloc((size_t)EMB * EMB);
    bf16* wtlv = alloc((size_t)EMB * EMB);
    bf16* qh = alloc((size_t)SEQ * EMB);
    bf16* ql = alloc((size_t)SEQ * EMB);
    bf16* kh = alloc((size_t)SEQ * EMB);
    bf16* kl = alloc((size_t)SEQ * EMB);
    bf16* vh = alloc((size_t)SEQ * EMB);
    bf16* vt = alloc((size_t)SEQ * EMB);
    (void)ws_size; (void)in_sizes; (void)n_in; (void)out_size;

    split_kernel<<<(SEQ * EMB / 4 + 255) / 256, 256, 0, stream>>>(x, xh, xl, SEQ * EMB / 4);
    dim3 wtb(32, 8);
    wtrans_kernel<<<dim3(32, 32), wtb, 0, stream>>>(Wq, wthq, wtlq);
    wtrans_kernel<<<dim3(32, 32), wtb, 0, stream>>>(Wk, wthk, wtlk);
    wtrans_kernel<<<dim3(32, 32), wtb, 0, stream>>>(Wv, wthv, wtlv);

    dim3 gg(EMB / 128, SEQ / 128);  // (8, 32)
    // Q gets the 1/sqrt(64) fold (exact power of two)
    proj_gemm<3><<<gg, 256, 0, stream>>>(xh, xl, wthq, wtlq, qh, ql, 0.125f);
    proj_gemm<3><<<gg, 256, 0, stream>>>(xh, xl, wthk, wtlk, kh, kl, 1.0f);
    proj_gemm<1><<<gg, 256, 0, stream>>>(xh, xl, wthv, wtlv, vh, nullptr, 1.0f);

    vtrans_kernel<<<dim3(SEQ / 64, NHD), dim3(64, 4), 0, stream>>>(vh, vt);

    attn_kernel<<<dim3(SEQ / 64, NHD), 256, 0, stream>>>(qh, ql, kh, kl, vt, out);
}

// Round 2
// 344.182 us; speedup vs baseline: 1.4938x; 1.4938x over previous
//
#include <hip/hip_runtime.h>
#include <hip/hip_bf16.h>

#define SEQ 4096
#define EMB 1024
#define NHD 16
#define HDD 64

using bf16 = __hip_bfloat16;
using bf16x8 = __attribute__((ext_vector_type(8))) short;
using f32x4  = __attribute__((ext_vector_type(4))) float;

#define MFMA16(a, b, c) __builtin_amdgcn_mfma_f32_16x16x32_bf16((a), (b), (c), 0, 0, 0)

__device__ __forceinline__ float b2f(bf16 b) { return __bfloat162float(b); }

__device__ __forceinline__ void gll16(const void* g, void* l) {
    __builtin_amdgcn_global_load_lds(
        (const __attribute__((address_space(1))) unsigned int*)g,
        (__attribute__((address_space(3))) unsigned int*)l, 16, 0, 0);
}

// ---------------- prep: split f32 -> hi/lo bf16 ----------------
__global__ void split_kernel(const float* __restrict__ src, bf16* __restrict__ hi,
                             bf16* __restrict__ lo, int n4) {
    int i = blockIdx.x * blockDim.x + threadIdx.x;
    if (i >= n4) return;
    float4 v = ((const float4*)src)[i];
    float vv[4] = {v.x, v.y, v.z, v.w};
#pragma unroll
    for (int j = 0; j < 4; j++) {
        bf16 h = __float2bfloat16(vv[j]);
        hi[i * 4 + j] = h;
        lo[i * 4 + j] = __float2bfloat16(vv[j] - b2f(h));
    }
}

// ---------------- prep: W[k][n] f32 -> Wt[n][k] hi/lo bf16 ----------------
__global__ void wtrans_kernel(const float* __restrict__ W, bf16* __restrict__ wth,
                              bf16* __restrict__ wtl) {
    __shared__ float tile[32][33];
    int n0 = blockIdx.x * 32, k0 = blockIdx.y * 32;
    int tx = threadIdx.x, ty = threadIdx.y;
    for (int r = ty; r < 32; r += 8)
        tile[r][tx] = W[(k0 + r) * EMB + n0 + tx];
    __syncthreads();
    for (int r = ty; r < 32; r += 8) {
        float v = tile[tx][r];  // = W[k0+tx][n0+r]
        bf16 h = __float2bfloat16(v);
        wth[(n0 + r) * EMB + k0 + tx] = h;
        wtl[(n0 + r) * EMB + k0 + tx] = __float2bfloat16(v - b2f(h));
    }
}

// ---------------- projection GEMM: C = A @ B (split bf16, fp32 acc) -------
template <int NTERMS>
__global__ __launch_bounds__(256) void proj_gemm(
    const bf16* __restrict__ Ah, const bf16* __restrict__ Al,
    const bf16* __restrict__ Bth, const bf16* __restrict__ Btl,
    bf16* __restrict__ Chi, bf16* __restrict__ Clo, float scale) {
    __shared__ __align__(16) bf16 lAh[128 * 40];
    __shared__ __align__(16) bf16 lAl[128 * 40];
    __shared__ __align__(16) bf16 lBh[128 * 40];
    __shared__ __align__(16) bf16 lBl[128 * 40];
    const int t = threadIdx.x;
    const int m0 = blockIdx.y * 128, n0 = blockIdx.x * 128;
    const int wid = t >> 6, lane = t & 63, lr = lane & 15, lg = lane >> 4;
    const int wr = (wid >> 1) * 64, wc = (wid & 1) * 64;

    f32x4 acc[4][4];
#pragma unroll
    for (int i = 0; i < 4; i++)
#pragma unroll
        for (int j = 0; j < 4; j++) acc[i][j] = (f32x4){0.f, 0.f, 0.f, 0.f};

    for (int k0 = 0; k0 < EMB; k0 += 32) {
#pragma unroll
        for (int c = t; c < 512; c += 256) {
            int row = c >> 2, slot = c & 3;
            *(uint4*)&lAh[row * 40 + slot * 8] =
                *(const uint4*)&Ah[(m0 + row) * EMB + k0 + slot * 8];
            *(uint4*)&lBh[row * 40 + slot * 8] =
                *(const uint4*)&Bth[(n0 + row) * EMB + k0 + slot * 8];
            if constexpr (NTERMS == 3) {
                *(uint4*)&lAl[row * 40 + slot * 8] =
                    *(const uint4*)&Al[(m0 + row) * EMB + k0 + slot * 8];
                *(uint4*)&lBl[row * 40 + slot * 8] =
                    *(const uint4*)&Btl[(n0 + row) * EMB + k0 + slot * 8];
            }
        }
        __syncthreads();
        bf16x8 fah[4], fbh[4], fal[4], fbl[4];
#pragma unroll
        for (int i = 0; i < 4; i++) {
            fah[i] = *(const bf16x8*)&lAh[(wr + i * 16 + lr) * 40 + lg * 8];
            fbh[i] = *(const bf16x8*)&lBh[(wc + i * 16 + lr) * 40 + lg * 8];
            if constexpr (NTERMS == 3) {
                fal[i] = *(const bf16x8*)&lAl[(wr + i * 16 + lr) * 40 + lg * 8];
                fbl[i] = *(const bf16x8*)&lBl[(wc + i * 16 + lr) * 40 + lg * 8];
            }
        }
#pragma unroll
        for (int i = 0; i < 4; i++)
#pragma unroll
            for (int j = 0; j < 4; j++) {
                acc[i][j] = MFMA16(fah[i], fbh[j], acc[i][j]);
                if constexpr (NTERMS == 3) {
                    acc[i][j] = MFMA16(fah[i], fbl[j], acc[i][j]);
                    acc[i][j] = MFMA16(fal[i], fbh[j], acc[i][j]);
                }
            }
        __syncthreads();
    }
#pragma unroll
    for (int i = 0; i < 4; i++)
#pragma unroll
        for (int j = 0; j < 4; j++)
#pragma unroll
            for (int q = 0; q < 4; q++) {
                float cv = acc[i][j][q] * scale;
                int m = m0 + wr + i * 16 + lg * 4 + q;
                int n = n0 + wc + j * 16 + lr;
                bf16 h = __float2bfloat16(cv);
                Chi[m * EMB + n] = h;
                if (Clo != nullptr)
                    Clo[m * EMB + n] = __float2bfloat16(cv - b2f(h));
            }
}

// ---------------- V transpose per head: vh[S][E] -> vt[H][D][S] ----------
__global__ void vtrans_kernel(const bf16* __restrict__ vh, bf16* __restrict__ vt) {
    __shared__ bf16 tile[64][65];
    int s0 = blockIdx.x * 64;
    int h = blockIdx.y;
    int tx = threadIdx.x, ty = threadIdx.y;  // (64,4)
    for (int r = ty; r < 64; r += 4)
        tile[r][tx] = vh[(s0 + r) * EMB + h * HDD + tx];
    __syncthreads();
    for (int r = ty; r < 64; r += 4)
        vt[(h * HDD + r) * SEQ + s0 + tx] = tile[tx][r];
}

// ---------------- fused flash attention (swapped-operand, swizzled LDS) ----
// grid: (SEQ/64, NHD). 256 thr = 4 waves, each wave owns 16 q-rows (q = lane&15).
// LDS: K hi/lo + V staged via global_load_lds with pre-swizzled global source:
//   LDS[row][slot] = G[row][slot ^ (row&7)]  (16B slots, 128B rows)
// so reads use byte ^= (row&7)<<4  -> conflict-free ds_read_b128.
// QK^T computed swapped (A=K, B=Q)  -> lane holds P[q=lane&15][k=kc*16+lg*4+j]
// PV   computed swapped (A=V, B=P)  -> O[d=lg*4+j+16df][q=lane&15]
// => softmax entirely per-lane (q fixed per lane), only 2 shfl_xor per reduce.
__global__ __launch_bounds__(256, 4) void attn_kernel(
    const bf16* __restrict__ qh, const bf16* __restrict__ ql,
    const bf16* __restrict__ kh, const bf16* __restrict__ kl,
    const bf16* __restrict__ vt, float* __restrict__ out) {
    __shared__ __align__(16) bf16 lKh[64 * 64];
    __shared__ __align__(16) bf16 lKl[64 * 64];
    __shared__ __align__(16) bf16 lV[64 * 64];
    __shared__ __align__(16) bf16 lP[4][16 * 64];
    const int t = threadIdx.x;
    const int q0 = blockIdx.x * 64;
    const int h = blockIdx.y;
    const int wid = t >> 6, lane = t & 63, lr = lane & 15, lg = lane >> 4;
    const int wq = wid * 16;

    // Q fragments direct from global (B-operand: row = lane&15 = q, k = lg*8+i)
    const bf16* qrh = qh + (size_t)(q0 + wq + lr) * EMB + h * HDD;
    const bf16* qrl = ql + (size_t)(q0 + wq + lr) * EMB + h * HDD;
    bf16x8 fqh[2], fql[2];
#pragma unroll
    for (int hf = 0; hf < 2; hf++) {
        fqh[hf] = *(const bf16x8*)(qrh + hf * 32 + lg * 8);
        fql[hf] = *(const bf16x8*)(qrl + hf * 32 + lg * 8);
    }

    f32x4 Ofr[4];
#pragma unroll
    for (int d = 0; d < 4; d++) Ofr[d] = (f32x4){0.f, 0.f, 0.f, 0.f};
    float Mr = -1e30f, Lr = 0.f;

    const int srow = lane >> 3;   // row-within-sect this lane stages
    const int slot = lane & 7;

    for (int s0 = 0; s0 < SEQ; s0 += 64) {
        __syncthreads();  // previous tile's compute done before overwrite
        // stage K hi/lo + V: 24 x 1KB chunks, 6 per wave, swizzled source
#pragma unroll
        for (int i = 0; i < 6; i++) {
            int cid = wid + i * 4;
            int sect = cid & 7;
            int r = sect * 8 + srow;
            int sb = (slot ^ (r & 7)) * 16;
            const char* g;
            bf16* l;
            if (cid < 8) {
                g = (const char*)kh + ((size_t)(s0 + r) * EMB + h * HDD) * 2 + sb;
                l = lKh + sect * 512;
            } else if (cid < 16) {
                g = (const char*)kl + ((size_t)(s0 + r) * EMB + h * HDD) * 2 + sb;
                l = lKl + sect * 512;
            } else {
                g = (const char*)vt + ((size_t)(h * HDD + r) * SEQ + s0) * 2 + sb;
                l = lV + sect * 512;
            }
            gll16(g, l);
        }
        __syncthreads();  // compiler drains vmcnt before barrier -> tile ready

        // S^T = K Q^T (A=K rows, B=Q rows). 3-term split, fp32 acc.
        f32x4 sfr[4];
#pragma unroll
        for (int kc = 0; kc < 4; kc++) {
            int row = kc * 16 + lr;
            const char* rbh = (const char*)lKh + row * 128;
            const char* rbl = (const char*)lKl + row * 128;
            f32x4 a = (f32x4){0.f, 0.f, 0.f, 0.f};
#pragma unroll
            for (int hf = 0; hf < 2; hf++) {
                int off = (hf * 64 + lg * 16) ^ ((row & 7) << 4);
                bf16x8 kbh = *(const bf16x8*)(rbh + off);
                bf16x8 kbl = *(const bf16x8*)(rbl + off);
                a = MFMA16(kbh, fqh[hf], a);
                a = MFMA16(kbh, fql[hf], a);
                a = MFMA16(kbl, fqh[hf], a);
            }
            sfr[kc] = a;  // sfr[kc][j] = S[q=lr][k = kc*16 + lg*4 + j]
        }

        // online softmax, per-lane row q=lr; reduce across lanes lr, lr+16/32/48
        float mx = sfr[0][0];
#pragma unroll
        for (int kc = 0; kc < 4; kc++)
#pragma unroll
            for (int j = 0; j < 4; j++) mx = fmaxf(mx, sfr[kc][j]);
        mx = fmaxf(mx, __shfl_xor(mx, 16));
        mx = fmaxf(mx, __shfl_xor(mx, 32));
        float mn = fmaxf(Mr, mx);
        float fac = __builtin_exp2f((Mr - mn) * 1.44269504f);
        Mr = mn;
        float ps = 0.f;
#pragma unroll
        for (int kc = 0; kc < 4; kc++)
#pragma unroll
            for (int j = 0; j < 4; j++) {
                float p = __builtin_exp2f((sfr[kc][j] - mn) * 1.44269504f);
                sfr[kc][j] = p;
                ps += p;
            }
        ps += __shfl_xor(ps, 16);
        ps += __shfl_xor(ps, 32);
        Lr = Lr * fac + ps;
#pragma unroll
        for (int d = 0; d < 4; d++)
#pragma unroll
            for (int j = 0; j < 4; j++) Ofr[d][j] *= fac;

        // P -> LDS: packed 8B per kc (k = kc*16+lg*4 .. +3), swizzled row q=lr
        {
            char* pw = (char*)&lP[wid][0] + lr * 128;
#pragma unroll
            for (int kc = 0; kc < 4; kc++) {
                __hip_bfloat162 p01 =
                    __float22bfloat162_rn(make_float2(sfr[kc][0], sfr[kc][1]));
                __hip_bfloat162 p23 =
                    __float22bfloat162_rn(make_float2(sfr[kc][2], sfr[kc][3]));
                uint2 w;
                w.x = *(unsigned int*)&p01;
                w.y = *(unsigned int*)&p23;
                *(uint2*)(pw + ((kc * 32 + lg * 8) ^ ((lr & 7) << 4))) = w;
            }
        }

        // O^T += V^T P^T  (A=V rows=d from lV[d][k], B=P rows=q from lP)
#pragma unroll
        for (int ks = 0; ks < 2; ks++) {
            const char* pb = (const char*)&lP[wid][0] + lr * 128 +
                             ((ks * 64 + lg * 16) ^ ((lr & 7) << 4));
            bf16x8 pf = *(const bf16x8*)pb;
#pragma unroll
            for (int df = 0; df < 4; df++) {
                int vrow = df * 16 + lr;
                const char* pv = (const char*)lV + vrow * 128 +
                                 ((ks * 64 + lg * 16) ^ ((vrow & 7) << 4));
                bf16x8 vf = *(const bf16x8*)pv;
                Ofr[df] = MFMA16(vf, pf, Ofr[df]);
            }
        }
    }

    // epilogue: O[d][q=lr] -> out[q0+wq+lr][h*64 + df*16 + lg*4 + j], 16B stores
    float inv = 1.0f / Lr;
    float* orow = out + (size_t)(q0 + wq + lr) * EMB + h * HDD;
#pragma unroll
    for (int df = 0; df < 4; df++) {
        float4 o = make_float4(Ofr[df][0] * inv, Ofr[df][1] * inv,
                               Ofr[df][2] * inv, Ofr[df][3] * inv);
        *(float4*)(orow + df * 16 + lg * 4) = o;
    }
}

// ---------------- launch ----------------
extern "C" void kernel_launch(void* const* d_in, const int* in_sizes, int n_in,
                              void* d_out, int out_size, void* d_ws, size_t ws_size,
                              hipStream_t stream) {
    const float* x = (const float*)d_in[0];
    const float* Wq = (const float*)d_in[1];
    const float* Wk = (const float*)d_in[2];
    const float* Wv = (const float*)d_in[3];
    float* out = (float*)d_out;

    char* ws = (char*)d_ws;
    size_t off = 0;
    auto alloc = [&](size_t elems) -> bf16* {
        bf16* p = (bf16*)(ws + off);
        off += elems * sizeof(bf16);
        return p;
    };
    bf16* xh = alloc((size_t)SEQ * EMB);
    bf16* xl = alloc((size_t)SEQ * EMB);
    bf16* wthq = alloc((size_t)EMB * EMB);
    bf16* wtlq = alloc((size_t)EMB * EMB);
    bf16* wthk = alloc((size_t)EMB * EMB);
    bf16* wtlk = alloc((size_t)EMB * EMB);
    bf16* wthv = alloc((size_t)EMB * EMB);
    bf16* wtlv = alloc((size_t)EMB * EMB);
    bf16* qh = alloc((size_t)SEQ * EMB);
    bf16* ql = alloc((size_t)SEQ * EMB);
    bf16* kh = alloc((size_t)SEQ * EMB);
    bf16* kl = alloc((size_t)SEQ * EMB);
    bf16* vh = alloc((size_t)SEQ * EMB);
    bf16* vt = alloc((size_t)SEQ * EMB);
    (void)ws_size; (void)in_sizes; (void)n_in; (void)out_size;

    split_kernel<<<(SEQ * EMB / 4 + 255) / 256, 256, 0, stream>>>(x, xh, xl, SEQ * EMB / 4);
    dim3 wtb(32, 8);
    wtrans_kernel<<<dim3(32, 32), wtb, 0, stream>>>(Wq, wthq, wtlq);
    wtrans_kernel<<<dim3(32, 32), wtb, 0, stream>>>(Wk, wthk, wtlk);
    wtrans_kernel<<<dim3(32, 32), wtb, 0, stream>>>(Wv, wthv, wtlv);

    dim3 gg(EMB / 128, SEQ / 128);  // (8, 32)
    proj_gemm<3><<<gg, 256, 0, stream>>>(xh, xl, wthq, wtlq, qh, ql, 0.125f);
    proj_gemm<3><<<gg, 256, 0, stream>>>(xh, xl, wthk, wtlk, kh, kl, 1.0f);
    proj_gemm<1><<<gg, 256, 0, stream>>>(xh, xl, wthv, wtlv, vh, nullptr, 1.0f);

    vtrans_kernel<<<dim3(SEQ / 64, NHD), dim3(64, 4), 0, stream>>>(vh, vt);

    attn_kernel<<<dim3(SEQ / 64, NHD), 256, 0, stream>>>(qh, ql, kh, kl, vt, out);
}

// Round 3
// 266.944 us; speedup vs baseline: 1.9261x; 1.2893x over previous
//
#include <hip/hip_runtime.h>
#include <hip/hip_bf16.h>

#define SEQ 4096
#define EMB 1024
#define NHD 16
#define HDD 64

using bf16 = __hip_bfloat16;
using bf16x8 = __attribute__((ext_vector_type(8))) short;
using f32x4  = __attribute__((ext_vector_type(4))) float;

#define MFMA16(a, b, c) __builtin_amdgcn_mfma_f32_16x16x32_bf16((a), (b), (c), 0, 0, 0)

// logit scale: 1/sqrt(64) * log2(e), folded into Q projection
#define QSCALE 0.1803368801111204f

__device__ __forceinline__ float b2f(bf16 b) { return __bfloat162float(b); }

__device__ __forceinline__ void gll16(const void* g, void* l) {
    __builtin_amdgcn_global_load_lds(
        (const __attribute__((address_space(1))) unsigned int*)g,
        (__attribute__((address_space(3))) unsigned int*)l, 16, 0, 0);
}

// ---------------- prep: split f32 -> hi/lo bf16 ----------------
__global__ void split_kernel(const float* __restrict__ src, bf16* __restrict__ hi,
                             bf16* __restrict__ lo, int n4) {
    int i = blockIdx.x * blockDim.x + threadIdx.x;
    if (i >= n4) return;
    float4 v = ((const float4*)src)[i];
    float vv[4] = {v.x, v.y, v.z, v.w};
#pragma unroll
    for (int j = 0; j < 4; j++) {
        bf16 h = __float2bfloat16(vv[j]);
        hi[i * 4 + j] = h;
        lo[i * 4 + j] = __float2bfloat16(vv[j] - b2f(h));
    }
}

// ---------------- prep: W[k][n] f32 -> Wt[n][k] hi/lo bf16 (all 3 W) ------
__global__ void wtrans_kernel(const float* __restrict__ Wq, const float* __restrict__ Wk,
                              const float* __restrict__ Wv,
                              bf16* __restrict__ thq, bf16* __restrict__ tlq,
                              bf16* __restrict__ thk, bf16* __restrict__ tlk,
                              bf16* __restrict__ thv, bf16* __restrict__ tlv) {
    __shared__ float tile[32][33];
    const float* W;
    bf16 *wth, *wtl;
    if (blockIdx.z == 0) { W = Wq; wth = thq; wtl = tlq; }
    else if (blockIdx.z == 1) { W = Wk; wth = thk; wtl = tlk; }
    else { W = Wv; wth = thv; wtl = tlv; }
    int n0 = blockIdx.x * 32, k0 = blockIdx.y * 32;
    int tx = threadIdx.x, ty = threadIdx.y;
    for (int r = ty; r < 32; r += 8)
        tile[r][tx] = W[(k0 + r) * EMB + n0 + tx];
    __syncthreads();
    for (int r = ty; r < 32; r += 8) {
        float v = tile[tx][r];  // = W[k0+tx][n0+r]
        bf16 h = __float2bfloat16(v);
        wth[(n0 + r) * EMB + k0 + tx] = h;
        wtl[(n0 + r) * EMB + k0 + tx] = __float2bfloat16(v - b2f(h));
    }
}

// ---------------- fused QKV projection GEMM ----------------
template <int NTERMS>
__device__ __forceinline__ void proj_loop(
    const bf16* __restrict__ Ah, const bf16* __restrict__ Al,
    const bf16* __restrict__ Bth, const bf16* __restrict__ Btl,
    bf16* lAh, bf16* lAl, bf16* lBh, bf16* lBl,
    int m0, int n0, int t, f32x4 (&acc)[4][4]) {
    const int wid = t >> 6, lane = t & 63, lr = lane & 15, lg = lane >> 4;
    const int wr = (wid >> 1) * 64, wc = (wid & 1) * 64;
    for (int k0 = 0; k0 < EMB; k0 += 32) {
#pragma unroll
        for (int c = t; c < 512; c += 256) {
            int row = c >> 2, slot = c & 3;
            *(uint4*)&lAh[row * 40 + slot * 8] =
                *(const uint4*)&Ah[(m0 + row) * EMB + k0 + slot * 8];
            *(uint4*)&lBh[row * 40 + slot * 8] =
                *(const uint4*)&Bth[(n0 + row) * EMB + k0 + slot * 8];
            if constexpr (NTERMS == 3) {
                *(uint4*)&lAl[row * 40 + slot * 8] =
                    *(const uint4*)&Al[(m0 + row) * EMB + k0 + slot * 8];
                *(uint4*)&lBl[row * 40 + slot * 8] =
                    *(const uint4*)&Btl[(n0 + row) * EMB + k0 + slot * 8];
            }
        }
        __syncthreads();
        bf16x8 fah[4], fbh[4], fal[4], fbl[4];
#pragma unroll
        for (int i = 0; i < 4; i++) {
            fah[i] = *(const bf16x8*)&lAh[(wr + i * 16 + lr) * 40 + lg * 8];
            fbh[i] = *(const bf16x8*)&lBh[(wc + i * 16 + lr) * 40 + lg * 8];
            if constexpr (NTERMS == 3) {
                fal[i] = *(const bf16x8*)&lAl[(wr + i * 16 + lr) * 40 + lg * 8];
                fbl[i] = *(const bf16x8*)&lBl[(wc + i * 16 + lr) * 40 + lg * 8];
            }
        }
#pragma unroll
        for (int i = 0; i < 4; i++)
#pragma unroll
            for (int j = 0; j < 4; j++) {
                acc[i][j] = MFMA16(fah[i], fbh[j], acc[i][j]);
                if constexpr (NTERMS == 3) {
                    acc[i][j] = MFMA16(fah[i], fbl[j], acc[i][j]);
                    acc[i][j] = MFMA16(fal[i], fbh[j], acc[i][j]);
                }
            }
        __syncthreads();
    }
}

// grid (24, 32): x covers 3*EMB columns (8 tiles each for Q,K,V), y covers SEQ rows
__global__ __launch_bounds__(256) void proj_qkv(
    const bf16* __restrict__ xh, const bf16* __restrict__ xl,
    const bf16* __restrict__ thq, const bf16* __restrict__ tlq,
    const bf16* __restrict__ thk, const bf16* __restrict__ tlk,
    const bf16* __restrict__ thv,
    bf16* __restrict__ qh, bf16* __restrict__ ql,
    bf16* __restrict__ kh, bf16* __restrict__ kl, bf16* __restrict__ vt) {
    __shared__ __align__(16) bf16 lAh[128 * 40];
    __shared__ __align__(16) bf16 lAl[128 * 40];
    __shared__ __align__(16) bf16 lBh[128 * 40];
    __shared__ __align__(16) bf16 lBl[128 * 40];
    const int t = threadIdx.x;
    const int m0 = blockIdx.y * 128;
    const int which = blockIdx.x >> 3;
    const int n0 = (blockIdx.x & 7) * 128;

    f32x4 acc[4][4];
#pragma unroll
    for (int i = 0; i < 4; i++)
#pragma unroll
        for (int j = 0; j < 4; j++) acc[i][j] = (f32x4){0.f, 0.f, 0.f, 0.f};

    if (which == 0)
        proj_loop<3>(xh, xl, thq, tlq, lAh, lAl, lBh, lBl, m0, n0, t, acc);
    else if (which == 1)
        proj_loop<3>(xh, xl, thk, tlk, lAh, lAl, lBh, lBl, m0, n0, t, acc);
    else
        proj_loop<1>(xh, xl, thv, nullptr, lAh, lAl, lBh, lBl, m0, n0, t, acc);

    const int wid = t >> 6, lane = t & 63, lr = lane & 15, lg = lane >> 4;
    const int wr = (wid >> 1) * 64, wc = (wid & 1) * 64;

    if (which == 2) {
        // V: write directly transposed vt[(h*64+d)*SEQ + m], 8B packed stores
#pragma unroll
        for (int i = 0; i < 4; i++)
#pragma unroll
            for (int j = 0; j < 4; j++) {
                int n = n0 + wc + j * 16 + lr;       // column in V = h*64 + d
                int m = m0 + wr + i * 16 + lg * 4;   // 4 consecutive seq rows
                __hip_bfloat162 p01 = __float22bfloat162_rn(
                    make_float2(acc[i][j][0], acc[i][j][1]));
                __hip_bfloat162 p23 = __float22bfloat162_rn(
                    make_float2(acc[i][j][2], acc[i][j][3]));
                uint2 w;
                w.x = *(unsigned int*)&p01;
                w.y = *(unsigned int*)&p23;
                *(uint2*)&vt[(size_t)n * SEQ + m] = w;
            }
    } else {
        float scale = (which == 0) ? QSCALE : 1.0f;
        bf16* Chi = (which == 0) ? qh : kh;
        bf16* Clo = (which == 0) ? ql : kl;
#pragma unroll
        for (int i = 0; i < 4; i++)
#pragma unroll
            for (int j = 0; j < 4; j++)
#pragma unroll
                for (int q = 0; q < 4; q++) {
                    float cv = acc[i][j][q] * scale;
                    int m = m0 + wr + i * 16 + lg * 4 + q;
                    int n = n0 + wc + j * 16 + lr;
                    bf16 hv = __float2bfloat16(cv);
                    Chi[m * EMB + n] = hv;
                    Clo[m * EMB + n] = __float2bfloat16(cv - b2f(hv));
                }
    }
}

// ---------------- fused flash attention (swapped-operand, swizzled LDS) ----
// grid: (SEQ/64, NHD). 256 thr = 4 waves, each wave owns 16 q-rows (q = lane&15).
// Logits arrive pre-scaled by log2(e)/8 (folded into Q) -> exp2 directly.
__global__ __launch_bounds__(256, 4) void attn_kernel(
    const bf16* __restrict__ qh, const bf16* __restrict__ ql,
    const bf16* __restrict__ kh, const bf16* __restrict__ kl,
    const bf16* __restrict__ vt, float* __restrict__ out) {
    __shared__ __align__(16) bf16 lKh[64 * 64];
    __shared__ __align__(16) bf16 lKl[64 * 64];
    __shared__ __align__(16) bf16 lV[64 * 64];
    __shared__ __align__(16) bf16 lP[4][16 * 64];
    const int t = threadIdx.x;
    const int q0 = blockIdx.x * 64;
    const int h = blockIdx.y;
    const int wid = t >> 6, lane = t & 63, lr = lane & 15, lg = lane >> 4;
    const int wq = wid * 16;

    // Q fragments direct from global (B-operand: row = lane&15 = q, k = lg*8+i)
    const bf16* qrh = qh + (size_t)(q0 + wq + lr) * EMB + h * HDD;
    const bf16* qrl = ql + (size_t)(q0 + wq + lr) * EMB + h * HDD;
    bf16x8 fqh[2], fql[2];
#pragma unroll
    for (int hf = 0; hf < 2; hf++) {
        fqh[hf] = *(const bf16x8*)(qrh + hf * 32 + lg * 8);
        fql[hf] = *(const bf16x8*)(qrl + hf * 32 + lg * 8);
    }

    // hoisted staging pointers: 6 chunks/wave, incremented per tile
    const int srow = lane >> 3, slot = lane & 7;
    const char* gp[6];
    bf16* lp[6];
#pragma unroll
    for (int i = 0; i < 6; i++) {
        int cid = wid + i * 4;
        int sect = cid & 7;
        int r = sect * 8 + srow;
        int sb = (slot ^ (r & 7)) * 16;
        if (i < 2) {
            gp[i] = (const char*)kh + ((size_t)r * EMB + h * HDD) * 2 + sb;
            lp[i] = lKh + sect * 512;
        } else if (i < 4) {
            gp[i] = (const char*)kl + ((size_t)r * EMB + h * HDD) * 2 + sb;
            lp[i] = lKl + sect * 512;
        } else {
            gp[i] = (const char*)vt + ((size_t)(h * HDD + r) * SEQ) * 2 + sb;
            lp[i] = lV + sect * 512;
        }
    }

    f32x4 Ofr[4];
#pragma unroll
    for (int d = 0; d < 4; d++) Ofr[d] = (f32x4){0.f, 0.f, 0.f, 0.f};
    float Mr = -1e30f, Lr = 0.f;

    for (int s0 = 0; s0 < SEQ; s0 += 64) {
        __syncthreads();  // previous tile's compute done before overwrite
#pragma unroll
        for (int i = 0; i < 6; i++) {
            gll16(gp[i], lp[i]);
            gp[i] += (i < 4) ? (size_t)(64 * EMB * 2) : (size_t)(64 * 2);
        }
        __syncthreads();  // vmcnt drained before barrier -> tile ready

        // S^T = K Q^T (A=K rows, B=Q rows). 3-term split, fp32 acc.
        __builtin_amdgcn_s_setprio(1);
        f32x4 sfr[4];
#pragma unroll
        for (int kc = 0; kc < 4; kc++) {
            int row = kc * 16 + lr;
            const char* rbh = (const char*)lKh + row * 128;
            const char* rbl = (const char*)lKl + row * 128;
            f32x4 a = (f32x4){0.f, 0.f, 0.f, 0.f};
#pragma unroll
            for (int hf = 0; hf < 2; hf++) {
                int off = (hf * 64 + lg * 16) ^ ((row & 7) << 4);
                bf16x8 kbh = *(const bf16x8*)(rbh + off);
                bf16x8 kbl = *(const bf16x8*)(rbl + off);
                a = MFMA16(kbh, fqh[hf], a);
                a = MFMA16(kbh, fql[hf], a);
                a = MFMA16(kbl, fqh[hf], a);
            }
            sfr[kc] = a;  // sfr[kc][j] = S2[q=lr][k = kc*16 + lg*4 + j]
        }
        __builtin_amdgcn_s_setprio(0);

        // online softmax (log2 domain), per-lane row q=lr
        float mx = sfr[0][0];
#pragma unroll
        for (int kc = 0; kc < 4; kc++)
#pragma unroll
            for (int j = 0; j < 4; j++) mx = fmaxf(mx, sfr[kc][j]);
        mx = fmaxf(mx, __shfl_xor(mx, 16));
        mx = fmaxf(mx, __shfl_xor(mx, 32));

        // defer-max (T13): skip rescale while growth <= 11.5 (= ln-domain 8)
        bool resc = !__all(mx <= Mr + 11.5f);
        float mn = resc ? fmaxf(Mr, mx) : Mr;
        float ps = 0.f;
#pragma unroll
        for (int kc = 0; kc < 4; kc++)
#pragma unroll
            for (int j = 0; j < 4; j++) {
                float p = __builtin_exp2f(sfr[kc][j] - mn);
                sfr[kc][j] = p;
                ps += p;
            }
        ps += __shfl_xor(ps, 16);
        ps += __shfl_xor(ps, 32);
        if (resc) {
            float fac = __builtin_exp2f(Mr - mn);
            Mr = mn;
            Lr = Lr * fac + ps;
#pragma unroll
            for (int d = 0; d < 4; d++)
#pragma unroll
                for (int j = 0; j < 4; j++) Ofr[d][j] *= fac;
        } else {
            Lr += ps;
        }

        // P -> LDS: packed 8B per kc, swizzled row q=lr
        {
            char* pw = (char*)&lP[wid][0] + lr * 128;
#pragma unroll
            for (int kc = 0; kc < 4; kc++) {
                __hip_bfloat162 p01 =
                    __float22bfloat162_rn(make_float2(sfr[kc][0], sfr[kc][1]));
                __hip_bfloat162 p23 =
                    __float22bfloat162_rn(make_float2(sfr[kc][2], sfr[kc][3]));
                uint2 w;
                w.x = *(unsigned int*)&p01;
                w.y = *(unsigned int*)&p23;
                *(uint2*)(pw + ((kc * 32 + lg * 8) ^ ((lr & 7) << 4))) = w;
            }
        }

        // O^T += V^T P^T  (A=V rows=d from lV[d][k], B=P rows=q from lP)
        __builtin_amdgcn_s_setprio(1);
#pragma unroll
        for (int ks = 0; ks < 2; ks++) {
            const char* pb = (const char*)&lP[wid][0] + lr * 128 +
                             ((ks * 64 + lg * 16) ^ ((lr & 7) << 4));
            bf16x8 pf = *(const bf16x8*)pb;
#pragma unroll
            for (int df = 0; df < 4; df++) {
                int vrow = df * 16 + lr;
                const char* pv = (const char*)lV + vrow * 128 +
                                 ((ks * 64 + lg * 16) ^ ((vrow & 7) << 4));
                bf16x8 vf = *(const bf16x8*)pv;
                Ofr[df] = MFMA16(vf, pf, Ofr[df]);
            }
        }
        __builtin_amdgcn_s_setprio(0);
    }

    // epilogue: O[d][q=lr] -> out[q0+wq+lr][h*64 + df*16 + lg*4 + j], 16B stores
    float inv = 1.0f / Lr;
    float* orow = out + (size_t)(q0 + wq + lr) * EMB + h * HDD;
#pragma unroll
    for (int df = 0; df < 4; df++) {
        float4 o = make_float4(Ofr[df][0] * inv, Ofr[df][1] * inv,
                               Ofr[df][2] * inv, Ofr[df][3] * inv);
        *(float4*)(orow + df * 16 + lg * 4) = o;
    }
}

// ---------------- launch ----------------
extern "C" void kernel_launch(void* const* d_in, const int* in_sizes, int n_in,
                              void* d_out, int out_size, void* d_ws, size_t ws_size,
                              hipStream_t stream) {
    const float* x = (const float*)d_in[0];
    const float* Wq = (const float*)d_in[1];
    const float* Wk = (const float*)d_in[2];
    const float* Wv = (const float*)d_in[3];
    float* out = (float*)d_out;

    char* ws = (char*)d_ws;
    size_t off = 0;
    auto alloc = [&](size_t elems) -> bf16* {
        bf16* p = (bf16*)(ws + off);
        off += elems * sizeof(bf16);
        return p;
    };
    bf16* xh = alloc((size_t)SEQ * EMB);
    bf16* xl = alloc((size_t)SEQ * EMB);
    bf16* wthq = alloc((size_t)EMB * EMB);
    bf16* wtlq = alloc((size_t)EMB * EMB);
    bf16* wthk = alloc((size_t)EMB * EMB);
    bf16* wtlk = alloc((size_t)EMB * EMB);
    bf16* wthv = alloc((size_t)EMB * EMB);
    bf16* wtlv = alloc((size_t)EMB * EMB);
    bf16* qh = alloc((size_t)SEQ * EMB);
    bf16* ql = alloc((size_t)SEQ * EMB);
    bf16* kh = alloc((size_t)SEQ * EMB);
    bf16* kl = alloc((size_t)SEQ * EMB);
    bf16* vt = alloc((size_t)SEQ * EMB);
    (void)ws_size; (void)in_sizes; (void)n_in; (void)out_size;

    split_kernel<<<(SEQ * EMB / 4 + 255) / 256, 256, 0, stream>>>(x, xh, xl, SEQ * EMB / 4);
    wtrans_kernel<<<dim3(32, 32, 3), dim3(32, 8), 0, stream>>>(
        Wq, Wk, Wv, wthq, wtlq, wthk, wtlk, wthv, wtlv);
    proj_qkv<<<dim3(24, 32), 256, 0, stream>>>(
        xh, xl, wthq, wtlq, wthk, wtlk, wthv, qh, ql, kh, kl, vt);
    attn_kernel<<<dim3(SEQ / 64, NHD), 256, 0, stream>>>(qh, ql, kh, kl, vt, out);
}

// Round 4
// 251.204 us; speedup vs baseline: 2.0468x; 1.0627x over previous
//
#include <hip/hip_runtime.h>
#include <hip/hip_bf16.h>

#define SEQ 4096
#define EMB 1024
#define NHD 16
#define HDD 64

using bf16 = __hip_bfloat16;
using bf16x8 = __attribute__((ext_vector_type(8))) short;
using f32x4  = __attribute__((ext_vector_type(4))) float;

#define MFMA16(a, b, c) __builtin_amdgcn_mfma_f32_16x16x32_bf16((a), (b), (c), 0, 0, 0)

// logit scale: 1/sqrt(64) * log2(e), folded into Q projection
#define QSCALE 0.1803368801111204f

__device__ __forceinline__ float b2f(bf16 b) { return __bfloat162float(b); }

__device__ __forceinline__ void gll16(const void* g, void* l) {
    __builtin_amdgcn_global_load_lds(
        (const __attribute__((address_space(1))) unsigned int*)g,
        (__attribute__((address_space(3))) unsigned int*)l, 16, 0, 0);
}

// ---------------- prep: split f32 -> hi/lo bf16 ----------------
__global__ void split_kernel(const float* __restrict__ src, bf16* __restrict__ hi,
                             bf16* __restrict__ lo, int n4) {
    int i = blockIdx.x * blockDim.x + threadIdx.x;
    if (i >= n4) return;
    float4 v = ((const float4*)src)[i];
    float vv[4] = {v.x, v.y, v.z, v.w};
#pragma unroll
    for (int j = 0; j < 4; j++) {
        bf16 h = __float2bfloat16(vv[j]);
        hi[i * 4 + j] = h;
        lo[i * 4 + j] = __float2bfloat16(vv[j] - b2f(h));
    }
}

// ---------------- prep: W[k][n] f32 -> Wt[n][k] hi/lo bf16 (all 3 W) ------
__global__ void wtrans_kernel(const float* __restrict__ Wq, const float* __restrict__ Wk,
                              const float* __restrict__ Wv,
                              bf16* __restrict__ thq, bf16* __restrict__ tlq,
                              bf16* __restrict__ thk, bf16* __restrict__ tlk,
                              bf16* __restrict__ thv, bf16* __restrict__ tlv) {
    __shared__ float tile[32][33];
    const float* W;
    bf16 *wth, *wtl;
    if (blockIdx.z == 0) { W = Wq; wth = thq; wtl = tlq; }
    else if (blockIdx.z == 1) { W = Wk; wth = thk; wtl = tlk; }
    else { W = Wv; wth = thv; wtl = tlv; }
    int n0 = blockIdx.x * 32, k0 = blockIdx.y * 32;
    int tx = threadIdx.x, ty = threadIdx.y;
    for (int r = ty; r < 32; r += 8)
        tile[r][tx] = W[(k0 + r) * EMB + n0 + tx];
    __syncthreads();
    for (int r = ty; r < 32; r += 8) {
        float v = tile[tx][r];  // = W[k0+tx][n0+r]
        bf16 h = __float2bfloat16(v);
        wth[(n0 + r) * EMB + k0 + tx] = h;
        wtl[(n0 + r) * EMB + k0 + tx] = __float2bfloat16(v - b2f(h));
    }
}

// ---------------- fused QKV projection GEMM ----------------
template <int NTERMS>
__device__ __forceinline__ void proj_loop(
    const bf16* __restrict__ Ah, const bf16* __restrict__ Al,
    const bf16* __restrict__ Bth, const bf16* __restrict__ Btl,
    bf16* lAh, bf16* lAl, bf16* lBh, bf16* lBl,
    int m0, int n0, int t, f32x4 (&acc)[4][4]) {
    const int wid = t >> 6, lane = t & 63, lr = lane & 15, lg = lane >> 4;
    const int wr = (wid >> 1) * 64, wc = (wid & 1) * 64;
    for (int k0 = 0; k0 < EMB; k0 += 32) {
#pragma unroll
        for (int c = t; c < 512; c += 256) {
            int row = c >> 2, slot = c & 3;
            *(uint4*)&lAh[row * 40 + slot * 8] =
                *(const uint4*)&Ah[(m0 + row) * EMB + k0 + slot * 8];
            *(uint4*)&lBh[row * 40 + slot * 8] =
                *(const uint4*)&Bth[(n0 + row) * EMB + k0 + slot * 8];
            if constexpr (NTERMS == 3) {
                *(uint4*)&lAl[row * 40 + slot * 8] =
                    *(const uint4*)&Al[(m0 + row) * EMB + k0 + slot * 8];
                *(uint4*)&lBl[row * 40 + slot * 8] =
                    *(const uint4*)&Btl[(n0 + row) * EMB + k0 + slot * 8];
            }
        }
        __syncthreads();
        bf16x8 fah[4], fbh[4], fal[4], fbl[4];
#pragma unroll
        for (int i = 0; i < 4; i++) {
            fah[i] = *(const bf16x8*)&lAh[(wr + i * 16 + lr) * 40 + lg * 8];
            fbh[i] = *(const bf16x8*)&lBh[(wc + i * 16 + lr) * 40 + lg * 8];
            if constexpr (NTERMS == 3) {
                fal[i] = *(const bf16x8*)&lAl[(wr + i * 16 + lr) * 40 + lg * 8];
                fbl[i] = *(const bf16x8*)&lBl[(wc + i * 16 + lr) * 40 + lg * 8];
            }
        }
#pragma unroll
        for (int i = 0; i < 4; i++)
#pragma unroll
            for (int j = 0; j < 4; j++) {
                acc[i][j] = MFMA16(fah[i], fbh[j], acc[i][j]);
                if constexpr (NTERMS == 3) {
                    acc[i][j] = MFMA16(fah[i], fbl[j], acc[i][j]);
                    acc[i][j] = MFMA16(fal[i], fbh[j], acc[i][j]);
                }
            }
        __syncthreads();
    }
}

// grid (24, 32): x covers 3*EMB columns (8 tiles each for Q,K,V), y covers SEQ rows
__global__ __launch_bounds__(256) void proj_qkv(
    const bf16* __restrict__ xh, const bf16* __restrict__ xl,
    const bf16* __restrict__ thq, const bf16* __restrict__ tlq,
    const bf16* __restrict__ thk, const bf16* __restrict__ tlk,
    const bf16* __restrict__ thv,
    bf16* __restrict__ qh, bf16* __restrict__ ql,
    bf16* __restrict__ kh, bf16* __restrict__ kl, bf16* __restrict__ vt) {
    __shared__ __align__(16) bf16 lAh[128 * 40];
    __shared__ __align__(16) bf16 lAl[128 * 40];
    __shared__ __align__(16) bf16 lBh[128 * 40];
    __shared__ __align__(16) bf16 lBl[128 * 40];
    const int t = threadIdx.x;
    const int m0 = blockIdx.y * 128;
    const int which = blockIdx.x >> 3;
    const int n0 = (blockIdx.x & 7) * 128;

    f32x4 acc[4][4];
#pragma unroll
    for (int i = 0; i < 4; i++)
#pragma unroll
        for (int j = 0; j < 4; j++) acc[i][j] = (f32x4){0.f, 0.f, 0.f, 0.f};

    if (which == 0)
        proj_loop<3>(xh, xl, thq, tlq, lAh, lAl, lBh, lBl, m0, n0, t, acc);
    else if (which == 1)
        proj_loop<3>(xh, xl, thk, tlk, lAh, lAl, lBh, lBl, m0, n0, t, acc);
    else
        proj_loop<1>(xh, xl, thv, nullptr, lAh, lAl, lBh, lBl, m0, n0, t, acc);

    const int wid = t >> 6, lane = t & 63, lr = lane & 15, lg = lane >> 4;
    const int wr = (wid >> 1) * 64, wc = (wid & 1) * 64;

    if (which == 2) {
        // V: write directly transposed vt[(h*64+d)*SEQ + m], 8B packed stores
#pragma unroll
        for (int i = 0; i < 4; i++)
#pragma unroll
            for (int j = 0; j < 4; j++) {
                int n = n0 + wc + j * 16 + lr;       // column in V = h*64 + d
                int m = m0 + wr + i * 16 + lg * 4;   // 4 consecutive seq rows
                __hip_bfloat162 p01 = __float22bfloat162_rn(
                    make_float2(acc[i][j][0], acc[i][j][1]));
                __hip_bfloat162 p23 = __float22bfloat162_rn(
                    make_float2(acc[i][j][2], acc[i][j][3]));
                uint2 w;
                w.x = *(unsigned int*)&p01;
                w.y = *(unsigned int*)&p23;
                *(uint2*)&vt[(size_t)n * SEQ + m] = w;
            }
    } else {
        float scale = (which == 0) ? QSCALE : 1.0f;
        bf16* Chi = (which == 0) ? qh : kh;
        bf16* Clo = (which == 0) ? ql : kl;
#pragma unroll
        for (int i = 0; i < 4; i++)
#pragma unroll
            for (int j = 0; j < 4; j++)
#pragma unroll
                for (int q = 0; q < 4; q++) {
                    float cv = acc[i][j][q] * scale;
                    int m = m0 + wr + i * 16 + lg * 4 + q;
                    int n = n0 + wc + j * 16 + lr;
                    bf16 hv = __float2bfloat16(cv);
                    Chi[m * EMB + n] = hv;
                    Clo[m * EMB + n] = __float2bfloat16(cv - b2f(hv));
                }
    }
}

// ---------------- fused flash attention v3 ----------------
// 8 waves (512 thr), QBLK=128 (16 q-rows/wave), KVBLK=64, double-buffered
// K/V LDS with prefetch-before-compute: the compiler's vmcnt(0) before
// s_barrier lands AFTER the compute phase, so staging latency hides under
// the 32 MFMA + softmax of the current tile.
// grid: 512 blocks (1D), XCD-swizzled so each XCD serves 2 heads (K/V L2-fit).
__global__ __launch_bounds__(512, 4) void attn_kernel(
    const bf16* __restrict__ qh, const bf16* __restrict__ ql,
    const bf16* __restrict__ kh, const bf16* __restrict__ kl,
    const bf16* __restrict__ vt, float* __restrict__ out) {
    // [buf][tensor: Kh,Kl,V][64 rows x 64 elems] + per-wave P. 64KB total.
    __shared__ __align__(16) bf16 lKV[2][3][64 * 64];
    __shared__ __align__(16) bf16 lP[8][16 * 64];
    const int t = threadIdx.x;
    // XCD-bijective swizzle (512 % 8 == 0): consecutive swz on one XCD share a head
    const int swz = (blockIdx.x & 7) * 64 + (blockIdx.x >> 3);
    const int h = swz >> 5;
    const int q0 = (swz & 31) * 128;
    const int wid = t >> 6, lane = t & 63, lr = lane & 15, lg = lane >> 4;
    const int wq = wid * 16;

    // Q fragments direct from global (B-operand: row = lane&15 = q, k = lg*8+i)
    const bf16* qrh = qh + (size_t)(q0 + wq + lr) * EMB + h * HDD;
    const bf16* qrl = ql + (size_t)(q0 + wq + lr) * EMB + h * HDD;
    bf16x8 fqh[2], fql[2];
#pragma unroll
    for (int hf = 0; hf < 2; hf++) {
        fqh[hf] = *(const bf16x8*)(qrh + hf * 32 + lg * 8);
        fql[hf] = *(const bf16x8*)(qrl + hf * 32 + lg * 8);
    }

    // staging: wave `wid` owns 8-row section `wid` of each tensor (3 gll/lane)
    const int srow = lane >> 3, slot = lane & 7;
    const int r = wid * 8 + srow;
    const int sb = (slot ^ (r & 7)) * 16;  // pre-swizzled global source
    const char* gp[3];
    gp[0] = (const char*)kh + ((size_t)r * EMB + h * HDD) * 2 + sb;
    gp[1] = (const char*)kl + ((size_t)r * EMB + h * HDD) * 2 + sb;
    gp[2] = (const char*)vt + ((size_t)(h * HDD + r) * SEQ) * 2 + sb;
    bf16* lp[3];
#pragma unroll
    for (int i = 0; i < 3; i++) lp[i] = &lKV[0][i][wid * 512];

    f32x4 Ofr[4];
#pragma unroll
    for (int d = 0; d < 4; d++) Ofr[d] = (f32x4){0.f, 0.f, 0.f, 0.f};
    float Mr = -1e30f, Lr = 0.f;

    // prologue: stage tile 0 into buf 0
#pragma unroll
    for (int i = 0; i < 3; i++) {
        gll16(gp[i], lp[i]);
        gp[i] += (i < 2) ? (size_t)(64 * EMB * 2) : (size_t)(64 * 2);
    }
    __syncthreads();

    for (int tk = 0; tk < SEQ / 64; tk++) {
        const int cur = tk & 1;
        // prefetch next tile into the other buffer (read at tk-1, barrier passed)
        if (tk < SEQ / 64 - 1) {
#pragma unroll
            for (int i = 0; i < 3; i++) {
                gll16(gp[i], lp[i] + (cur ^ 1) * 12288);
                gp[i] += (i < 2) ? (size_t)(64 * EMB * 2) : (size_t)(64 * 2);
            }
        }
        const char* cKh = (const char*)&lKV[cur][0][0];
        const char* cKl = (const char*)&lKV[cur][1][0];
        const char* cV  = (const char*)&lKV[cur][2][0];

        // S^T = K Q^T (A=K rows, B=Q rows). 3-term split, fp32 acc.
        __builtin_amdgcn_s_setprio(1);
        f32x4 sfr[4];
#pragma unroll
        for (int kc = 0; kc < 4; kc++) {
            int row = kc * 16 + lr;
            const char* rbh = cKh + row * 128;
            const char* rbl = cKl + row * 128;
            f32x4 a = (f32x4){0.f, 0.f, 0.f, 0.f};
#pragma unroll
            for (int hf = 0; hf < 2; hf++) {
                int off = (hf * 64 + lg * 16) ^ ((row & 7) << 4);
                bf16x8 kbh = *(const bf16x8*)(rbh + off);
                bf16x8 kbl = *(const bf16x8*)(rbl + off);
                a = MFMA16(kbh, fqh[hf], a);
                a = MFMA16(kbh, fql[hf], a);
                a = MFMA16(kbl, fqh[hf], a);
            }
            sfr[kc] = a;  // sfr[kc][j] = S2[q=lr][k = kc*16 + lg*4 + j]
        }
        __builtin_amdgcn_s_setprio(0);

        // online softmax (log2 domain), per-lane row q=lr
        float mx = sfr[0][0];
#pragma unroll
        for (int kc = 0; kc < 4; kc++)
#pragma unroll
            for (int j = 0; j < 4; j++) mx = fmaxf(mx, sfr[kc][j]);
        mx = fmaxf(mx, __shfl_xor(mx, 16));
        mx = fmaxf(mx, __shfl_xor(mx, 32));

        // defer-max (T13): skip rescale while growth <= 11.5 (= ln-domain 8)
        bool resc = !__all(mx <= Mr + 11.5f);
        float mn = resc ? fmaxf(Mr, mx) : Mr;
        float ps = 0.f;
#pragma unroll
        for (int kc = 0; kc < 4; kc++)
#pragma unroll
            for (int j = 0; j < 4; j++) {
                float p = __builtin_exp2f(sfr[kc][j] - mn);
                sfr[kc][j] = p;
                ps += p;
            }
        ps += __shfl_xor(ps, 16);
        ps += __shfl_xor(ps, 32);
        if (resc) {
            float fac = __builtin_exp2f(Mr - mn);
            Mr = mn;
            Lr = Lr * fac + ps;
#pragma unroll
            for (int d = 0; d < 4; d++)
#pragma unroll
                for (int j = 0; j < 4; j++) Ofr[d][j] *= fac;
        } else {
            Lr += ps;
        }

        // P -> LDS: packed 8B per kc, swizzled row q=lr (per-wave region)
        {
            char* pw = (char*)&lP[wid][0] + lr * 128;
#pragma unroll
            for (int kc = 0; kc < 4; kc++) {
                __hip_bfloat162 p01 =
                    __float22bfloat162_rn(make_float2(sfr[kc][0], sfr[kc][1]));
                __hip_bfloat162 p23 =
                    __float22bfloat162_rn(make_float2(sfr[kc][2], sfr[kc][3]));
                uint2 w;
                w.x = *(unsigned int*)&p01;
                w.y = *(unsigned int*)&p23;
                *(uint2*)(pw + ((kc * 32 + lg * 8) ^ ((lr & 7) << 4))) = w;
            }
        }

        // O^T += V^T P^T  (A=V rows=d from lV[d][k], B=P rows=q from lP)
        __builtin_amdgcn_s_setprio(1);
#pragma unroll
        for (int ks = 0; ks < 2; ks++) {
            const char* pb = (const char*)&lP[wid][0] + lr * 128 +
                             ((ks * 64 + lg * 16) ^ ((lr & 7) << 4));
            bf16x8 pf = *(const bf16x8*)pb;
#pragma unroll
            for (int df = 0; df < 4; df++) {
                int vrow = df * 16 + lr;
                const char* pv = cV + vrow * 128 +
                                 ((ks * 64 + lg * 16) ^ ((vrow & 7) << 4));
                bf16x8 vf = *(const bf16x8*)pv;
                Ofr[df] = MFMA16(vf, pf, Ofr[df]);
            }
        }
        __builtin_amdgcn_s_setprio(0);

        // single barrier per tile: drains this tile's prefetch (vmcnt(0)) and
        // releases buf[cur] for overwrite next iteration
        __syncthreads();
    }

    // epilogue: O[d][q=lr] -> out[q0+wq+lr][h*64 + df*16 + lg*4 + j], 16B stores
    float inv = 1.0f / Lr;
    float* orow = out + (size_t)(q0 + wq + lr) * EMB + h * HDD;
#pragma unroll
    for (int df = 0; df < 4; df++) {
        float4 o = make_float4(Ofr[df][0] * inv, Ofr[df][1] * inv,
                               Ofr[df][2] * inv, Ofr[df][3] * inv);
        *(float4*)(orow + df * 16 + lg * 4) = o;
    }
}

// ---------------- launch ----------------
extern "C" void kernel_launch(void* const* d_in, const int* in_sizes, int n_in,
                              void* d_out, int out_size, void* d_ws, size_t ws_size,
                              hipStream_t stream) {
    const float* x = (const float*)d_in[0];
    const float* Wq = (const float*)d_in[1];
    const float* Wk = (const float*)d_in[2];
    const float* Wv = (const float*)d_in[3];
    float* out = (float*)d_out;

    char* ws = (char*)d_ws;
    size_t off = 0;
    auto alloc = [&](size_t elems) -> bf16* {
        bf16* p = (bf16*)(ws + off);
        off += elems * sizeof(bf16);
        return p;
    };
    bf16* xh = alloc((size_t)SEQ * EMB);
    bf16* xl = alloc((size_t)SEQ * EMB);
    bf16* wthq = alloc((size_t)EMB * EMB);
    bf16* wtlq = alloc((size_t)EMB * EMB);
    bf16* wthk = alloc((size_t)EMB * EMB);
    bf16* wtlk = alloc((size_t)EMB * EMB);
    bf16* wthv = alloc((size_t)EMB * EMB);
    bf16* wtlv = alloc((size_t)EMB * EMB);
    bf16* qh = alloc((size_t)SEQ * EMB);
    bf16* ql = alloc((size_t)SEQ * EMB);
    bf16* kh = alloc((size_t)SEQ * EMB);
    bf16* kl = alloc((size_t)SEQ * EMB);
    bf16* vt = alloc((size_t)SEQ * EMB);
    (void)ws_size; (void)in_sizes; (void)n_in; (void)out_size;

    split_kernel<<<(SEQ * EMB / 4 + 255) / 256, 256, 0, stream>>>(x, xh, xl, SEQ * EMB / 4);
    wtrans_kernel<<<dim3(32, 32, 3), dim3(32, 8), 0, stream>>>(
        Wq, Wk, Wv, wthq, wtlq, wthk, wtlk, wthv, wtlv);
    proj_qkv<<<dim3(24, 32), 256, 0, stream>>>(
        xh, xl, wthq, wtlq, wthk, wtlk, wthv, qh, ql, kh, kl, vt);
    attn_kernel<<<512, 512, 0, stream>>>(qh, ql, kh, kl, vt, out);
}

// Round 7
// 243.407 us; speedup vs baseline: 2.1123x; 1.0320x over previous
//
#include <hip/hip_runtime.h>
#include <hip/hip_bf16.h>

#define SEQ 4096
#define EMB 1024
#define NHD 16
#define HDD 64

using bf16 = __hip_bfloat16;
using bf16x8 = __attribute__((ext_vector_type(8))) short;
using f32x4  = __attribute__((ext_vector_type(4))) float;
using f32x16 = __attribute__((ext_vector_type(16))) float;
using u32x4  = __attribute__((ext_vector_type(4))) unsigned int;
using u32x2  = __attribute__((ext_vector_type(2))) unsigned int;

#define MFMA16(a, b, c) __builtin_amdgcn_mfma_f32_16x16x32_bf16((a), (b), (c), 0, 0, 0)
#define MFMA32(a, b, c) __builtin_amdgcn_mfma_f32_32x32x16_bf16((a), (b), (c), 0, 0, 0)

// logit scale: 1/sqrt(64) * log2(e), folded into Q projection
#define QSCALE 0.1803368801111204f

__device__ __forceinline__ float b2f(bf16 b) { return __bfloat162float(b); }

__device__ __forceinline__ void gll16(const void* g, void* l) {
    __builtin_amdgcn_global_load_lds(
        (const __attribute__((address_space(1))) unsigned int*)g,
        (__attribute__((address_space(3))) unsigned int*)l, 16, 0, 0);
}

__device__ __forceinline__ unsigned pack_bf16x2(float a, float b) {
    __hip_bfloat162 p = __float22bfloat162_rn(make_float2(a, b));
    unsigned w;
    __builtin_memcpy(&w, &p, 4);
    return w;
}

// ---------------- prep: split f32 -> hi/lo bf16 ----------------
__global__ void split_kernel(const float* __restrict__ src, bf16* __restrict__ hi,
                             bf16* __restrict__ lo, int n4) {
    int i = blockIdx.x * blockDim.x + threadIdx.x;
    if (i >= n4) return;
    float4 v = ((const float4*)src)[i];
    float vv[4] = {v.x, v.y, v.z, v.w};
#pragma unroll
    for (int j = 0; j < 4; j++) {
        bf16 h = __float2bfloat16(vv[j]);
        hi[i * 4 + j] = h;
        lo[i * 4 + j] = __float2bfloat16(vv[j] - b2f(h));
    }
}

// ---------------- prep: W[k][n] f32 -> Wt[n][k] hi/lo bf16 (all 3 W) ------
__global__ void wtrans_kernel(const float* __restrict__ Wq, const float* __restrict__ Wk,
                              const float* __restrict__ Wv,
                              bf16* __restrict__ thq, bf16* __restrict__ tlq,
                              bf16* __restrict__ thk, bf16* __restrict__ tlk,
                              bf16* __restrict__ thv, bf16* __restrict__ tlv) {
    __shared__ float tile[32][33];
    const float* W;
    bf16 *wth, *wtl;
    if (blockIdx.z == 0) { W = Wq; wth = thq; wtl = tlq; }
    else if (blockIdx.z == 1) { W = Wk; wth = thk; wtl = tlk; }
    else { W = Wv; wth = thv; wtl = tlv; }
    int n0 = blockIdx.x * 32, k0 = blockIdx.y * 32;
    int tx = threadIdx.x, ty = threadIdx.y;
    for (int r = ty; r < 32; r += 8)
        tile[r][tx] = W[(k0 + r) * EMB + n0 + tx];
    __syncthreads();
    for (int r = ty; r < 32; r += 8) {
        float v = tile[tx][r];  // = W[k0+tx][n0+r]
        bf16 h = __float2bfloat16(v);
        wth[(n0 + r) * EMB + k0 + tx] = h;
        wtl[(n0 + r) * EMB + k0 + tx] = __float2bfloat16(v - b2f(h));
    }
}

// ---------------- fused QKV projection GEMM ----------------
template <int NTERMS>
__device__ __forceinline__ void proj_loop(
    const bf16* __restrict__ Ah, const bf16* __restrict__ Al,
    const bf16* __restrict__ Bth, const bf16* __restrict__ Btl,
    bf16* lAh, bf16* lAl, bf16* lBh, bf16* lBl,
    int m0, int n0, int t, f32x4 (&acc)[4][4]) {
    const int wid = t >> 6, lane = t & 63, lr = lane & 15, lg = lane >> 4;
    const int wr = (wid >> 1) * 64, wc = (wid & 1) * 64;
    for (int k0 = 0; k0 < EMB; k0 += 32) {
#pragma unroll
        for (int c = t; c < 512; c += 256) {
            int row = c >> 2, slot = c & 3;
            *(uint4*)&lAh[row * 40 + slot * 8] =
                *(const uint4*)&Ah[(m0 + row) * EMB + k0 + slot * 8];
            *(uint4*)&lBh[row * 40 + slot * 8] =
                *(const uint4*)&Bth[(n0 + row) * EMB + k0 + slot * 8];
            if constexpr (NTERMS == 3) {
                *(uint4*)&lAl[row * 40 + slot * 8] =
                    *(const uint4*)&Al[(m0 + row) * EMB + k0 + slot * 8];
                *(uint4*)&lBl[row * 40 + slot * 8] =
                    *(const uint4*)&Btl[(n0 + row) * EMB + k0 + slot * 8];
            }
        }
        __syncthreads();
        bf16x8 fah[4], fbh[4], fal[4], fbl[4];
#pragma unroll
        for (int i = 0; i < 4; i++) {
            fah[i] = *(const bf16x8*)&lAh[(wr + i * 16 + lr) * 40 + lg * 8];
            fbh[i] = *(const bf16x8*)&lBh[(wc + i * 16 + lr) * 40 + lg * 8];
            if constexpr (NTERMS == 3) {
                fal[i] = *(const bf16x8*)&lAl[(wr + i * 16 + lr) * 40 + lg * 8];
                fbl[i] = *(const bf16x8*)&lBl[(wc + i * 16 + lr) * 40 + lg * 8];
            }
        }
#pragma unroll
        for (int i = 0; i < 4; i++)
#pragma unroll
            for (int j = 0; j < 4; j++) {
                acc[i][j] = MFMA16(fah[i], fbh[j], acc[i][j]);
                if constexpr (NTERMS == 3) {
                    acc[i][j] = MFMA16(fah[i], fbl[j], acc[i][j]);
                    acc[i][j] = MFMA16(fal[i], fbh[j], acc[i][j]);
                }
            }
        __syncthreads();
    }
}

// grid (24, 32): x covers 3*EMB columns (8 tiles each for Q,K,V), y covers SEQ rows
__global__ __launch_bounds__(256) void proj_qkv(
    const bf16* __restrict__ xh, const bf16* __restrict__ xl,
    const bf16* __restrict__ thq, const bf16* __restrict__ tlq,
    const bf16* __restrict__ thk, const bf16* __restrict__ tlk,
    const bf16* __restrict__ thv,
    bf16* __restrict__ qh, bf16* __restrict__ ql,
    bf16* __restrict__ kh, bf16* __restrict__ kl, bf16* __restrict__ vt) {
    __shared__ __align__(16) bf16 lAh[128 * 40];
    __shared__ __align__(16) bf16 lAl[128 * 40];
    __shared__ __align__(16) bf16 lBh[128 * 40];
    __shared__ __align__(16) bf16 lBl[128 * 40];
    const int t = threadIdx.x;
    const int m0 = blockIdx.y * 128;
    const int which = blockIdx.x >> 3;
    const int n0 = (blockIdx.x & 7) * 128;

    f32x4 acc[4][4];
#pragma unroll
    for (int i = 0; i < 4; i++)
#pragma unroll
        for (int j = 0; j < 4; j++) acc[i][j] = (f32x4){0.f, 0.f, 0.f, 0.f};

    if (which == 0)
        proj_loop<3>(xh, xl, thq, tlq, lAh, lAl, lBh, lBl, m0, n0, t, acc);
    else if (which == 1)
        proj_loop<3>(xh, xl, thk, tlk, lAh, lAl, lBh, lBl, m0, n0, t, acc);
    else
        proj_loop<1>(xh, xl, thv, nullptr, lAh, lAl, lBh, lBl, m0, n0, t, acc);

    const int wid = t >> 6, lane = t & 63, lr = lane & 15, lg = lane >> 4;
    const int wr = (wid >> 1) * 64, wc = (wid & 1) * 64;

    if (which == 2) {
        // V: write directly transposed vt[(h*64+d)*SEQ + m], 8B packed stores
#pragma unroll
        for (int i = 0; i < 4; i++)
#pragma unroll
            for (int j = 0; j < 4; j++) {
                int n = n0 + wc + j * 16 + lr;       // column in V = h*64 + d
                int m = m0 + wr + i * 16 + lg * 4;   // 4 consecutive seq rows
                uint2 w;
                w.x = pack_bf16x2(acc[i][j][0], acc[i][j][1]);
                w.y = pack_bf16x2(acc[i][j][2], acc[i][j][3]);
                *(uint2*)&vt[(size_t)n * SEQ + m] = w;
            }
    } else {
        float scale = (which == 0) ? QSCALE : 1.0f;
        bf16* Chi = (which == 0) ? qh : kh;
        bf16* Clo = (which == 0) ? ql : kl;
#pragma unroll
        for (int i = 0; i < 4; i++)
#pragma unroll
            for (int j = 0; j < 4; j++)
#pragma unroll
                for (int q = 0; q < 4; q++) {
                    float cv = acc[i][j][q] * scale;
                    int m = m0 + wr + i * 16 + lg * 4 + q;
                    int n = n0 + wc + j * 16 + lr;
                    bf16 hv = __float2bfloat16(cv);
                    Chi[m * EMB + n] = hv;
                    Clo[m * EMB + n] = __float2bfloat16(cv - b2f(hv));
                }
    }
}

// ---------------- fused flash attention v4: 32x32 MFMA, in-register P ------
// 8 waves (512 thr), QBLK=256 (32 q-rows/wave), KVBLK=64, double-buffered
// K/V in LDS (48KB), grid 256 = 1 block/CU, XCD-swizzled (2 heads/XCD).
// QK^T swapped (A=K, B=Q): C[k][q], lane q = lane&31, 32 P-vals in regs.
// P -> PV B-fragment entirely in registers: cvt_pk pairs + permlane32_swap.
// Semantics: swap(D,S) exchanges D[lanes 32..63] <-> S[lanes 0..31], so
//   swap(w01, w45) -> new w01 = fw0 {hi0:(0,1), hi1:(8,9)},
//                     new w45 = fw2 {hi0:(4,5), hi1:(12,13)}  (early op FIRST).
// PV swapped (A=V from lV[d][k], B=P): O^T[d][q] accumulates in 2x f32x16.
__global__ __launch_bounds__(512, 2) void attn_kernel(
    const bf16* __restrict__ qh, const bf16* __restrict__ ql,
    const bf16* __restrict__ kh, const bf16* __restrict__ kl,
    const bf16* __restrict__ vt, float* __restrict__ out) {
    __shared__ __align__(16) bf16 lKV[2][3][64 * 64];  // 48 KB
    const int t = threadIdx.x;
    // XCD-bijective swizzle (256 % 8 == 0): 32 consecutive swz per XCD = 2 heads
    const int swz = (blockIdx.x & 7) * 32 + (blockIdx.x >> 3);
    const int h = swz >> 4;
    const int q0 = (swz & 15) * 256;
    const int wid = t >> 6, lane = t & 63;
    const int qq = lane & 31, hi = lane >> 5;
    const int qrow = q0 + wid * 32 + qq;

    // Q fragments (B-operand): col q = lane&31, k(d) = ds*16 + hi*8 + i
    bf16x8 fqh[4], fql[4];
    {
        const bf16* qbh = qh + (size_t)qrow * EMB + h * HDD + hi * 8;
        const bf16* qbl = ql + (size_t)qrow * EMB + h * HDD + hi * 8;
#pragma unroll
        for (int ds = 0; ds < 4; ds++) {
            fqh[ds] = *(const bf16x8*)(qbh + ds * 16);
            fql[ds] = *(const bf16x8*)(qbl + ds * 16);
        }
    }

    // staging: wave wid owns rows [wid*8, wid*8+8) of Kh/Kl/V (3 gll/lane/tile)
    const int srow = lane >> 3, slot = lane & 7;
    const int r = wid * 8 + srow;
    const int sb = (slot ^ (r & 7)) * 16;  // pre-swizzled global source
    const char* gp[3];
    gp[0] = (const char*)kh + ((size_t)r * EMB + h * HDD) * 2 + sb;
    gp[1] = (const char*)kl + ((size_t)r * EMB + h * HDD) * 2 + sb;
    gp[2] = (const char*)vt + ((size_t)(h * HDD + r) * SEQ) * 2 + sb;
    bf16* lp[3];
#pragma unroll
    for (int i = 0; i < 3; i++) lp[i] = &lKV[0][i][wid * 512];

    f32x16 Ofr[2];
#pragma unroll
    for (int db = 0; db < 2; db++)
#pragma unroll
        for (int rg = 0; rg < 16; rg++) Ofr[db][rg] = 0.f;
    float Mr = -1e30f, Lr = 0.f;

    // prologue: stage tile 0 into buf 0
#pragma unroll
    for (int i = 0; i < 3; i++) {
        gll16(gp[i], lp[i]);
        gp[i] += (i < 2) ? (size_t)(64 * EMB * 2) : (size_t)(64 * 2);
    }
    __syncthreads();

    for (int tk = 0; tk < SEQ / 64; tk++) {
        const int cur = tk & 1;
        if (tk < SEQ / 64 - 1) {
#pragma unroll
            for (int i = 0; i < 3; i++) {
                gll16(gp[i], lp[i] + (cur ^ 1) * 12288);
                gp[i] += (i < 2) ? (size_t)(64 * EMB * 2) : (size_t)(64 * 2);
            }
        }
        const char* cKh = (const char*)&lKV[cur][0][0];
        const char* cKl = (const char*)&lKV[cur][1][0];
        const char* cV  = (const char*)&lKV[cur][2][0];

        // S^T = K Q^T, 3-term split, fp32 acc. A-frag row k = kb*32 + (lane&31)
        __builtin_amdgcn_s_setprio(1);
        f32x16 sfr[2];
#pragma unroll
        for (int kb = 0; kb < 2; kb++) {
            const int row = kb * 32 + qq;
            const char* rbh = cKh + row * 128;
            const char* rbl = cKl + row * 128;
            const int sw = (row & 7) << 4;
            f32x16 a;
#pragma unroll
            for (int rg = 0; rg < 16; rg++) a[rg] = 0.f;
#pragma unroll
            for (int ds = 0; ds < 4; ds++) {
                const int off = (ds * 32 + hi * 16) ^ sw;
                bf16x8 kbh_ = *(const bf16x8*)(rbh + off);
                bf16x8 kbl_ = *(const bf16x8*)(rbl + off);
                a = MFMA32(kbh_, fqh[ds], a);
                a = MFMA32(kbh_, fql[ds], a);
                a = MFMA32(kbl_, fqh[ds], a);
            }
            sfr[kb] = a;  // sfr[kb][reg]: k = kb*32 + (reg&3)+8*(reg>>2)+4*hi
        }
        __builtin_amdgcn_s_setprio(0);

        // online softmax (log2 domain); q fixed per lane; partner = lane^32
        float mx = sfr[0][0];
#pragma unroll
        for (int kb = 0; kb < 2; kb++)
#pragma unroll
            for (int rg = 0; rg < 16; rg++) mx = fmaxf(mx, sfr[kb][rg]);
        mx = fmaxf(mx, __shfl_xor(mx, 32));

        // defer-max (T13): skip rescale while growth <= 11.5 (= ln-domain 8)
        bool resc = !__all(mx <= Mr + 11.5f);
        float mn = resc ? fmaxf(Mr, mx) : Mr;
        float ps = 0.f;
#pragma unroll
        for (int kb = 0; kb < 2; kb++)
#pragma unroll
            for (int rg = 0; rg < 16; rg++) {
                float p = __builtin_exp2f(sfr[kb][rg] - mn);
                sfr[kb][rg] = p;
                ps += p;
            }
        ps += __shfl_xor(ps, 32);
        if (resc) {
            float fac = __builtin_exp2f(Mr - mn);
            Mr = mn;
            Lr = Lr * fac + ps;
#pragma unroll
            for (int db = 0; db < 2; db++)
#pragma unroll
                for (int rg = 0; rg < 16; rg++) Ofr[db][rg] *= fac;
        } else {
            Lr += ps;
        }

        // pack P to bf16 + permlane32_swap -> PV B-frags, zero LDS traffic.
        // slice sl covers k = [sl*16, sl*16+16); lane needs k = sl*16 + hi*8 + i
        bf16x8 pf[4];
#pragma unroll
        for (int sl = 0; sl < 4; sl++) {
            const int kb = sl >> 1, s8 = (sl & 1) * 8;
            unsigned w01 = pack_bf16x2(sfr[kb][s8 + 0], sfr[kb][s8 + 1]);
            unsigned w23 = pack_bf16x2(sfr[kb][s8 + 2], sfr[kb][s8 + 3]);
            unsigned w45 = pack_bf16x2(sfr[kb][s8 + 4], sfr[kb][s8 + 5]);
            unsigned w67 = pack_bf16x2(sfr[kb][s8 + 6], sfr[kb][s8 + 7]);
            // swap(D,S): D[32:63] <-> S[0:31]; early word FIRST.
            u32x2 r0 = __builtin_amdgcn_permlane32_swap(w01, w45, false, false);
            u32x2 r1 = __builtin_amdgcn_permlane32_swap(w23, w67, false, false);
            u32x4 fw = {r0[0], r1[0], r0[1], r1[1]};  // fw0,fw1,fw2,fw3
            bf16x8 pfv;
            __builtin_memcpy(&pfv, &fw, 16);
            pf[sl] = pfv;
        }

        // O^T += V^T P^T: A-frag row d = db*32 + (lane&31) from lV[d][k]
        __builtin_amdgcn_s_setprio(1);
#pragma unroll
        for (int sl = 0; sl < 4; sl++) {
#pragma unroll
            for (int db = 0; db < 2; db++) {
                const int vd = db * 32 + qq;
                const char* pv =
                    cV + vd * 128 + ((sl * 32 + hi * 16) ^ ((vd & 7) << 4));
                bf16x8 vf = *(const bf16x8*)pv;
                Ofr[db] = MFMA32(vf, pf[sl], Ofr[db]);
            }
        }
        __builtin_amdgcn_s_setprio(0);

        // one barrier per tile: drains prefetch (vmcnt0) + releases buf[cur]
        __syncthreads();
    }

    // epilogue: O^T[d][q] -> out[qrow][h*64 + d], d = db*32 + rg*8 + hi*4 + 0..3
    float inv = 1.0f / Lr;
    float* orow = out + (size_t)qrow * EMB + h * HDD;
#pragma unroll
    for (int db = 0; db < 2; db++)
#pragma unroll
        for (int rg = 0; rg < 4; rg++) {
            float4 o = make_float4(Ofr[db][rg * 4 + 0] * inv,
                                   Ofr[db][rg * 4 + 1] * inv,
                                   Ofr[db][rg * 4 + 2] * inv,
                                   Ofr[db][rg * 4 + 3] * inv);
            *(float4*)(orow + db * 32 + rg * 8 + hi * 4) = o;
        }
}

// ---------------- launch ----------------
extern "C" void kernel_launch(void* const* d_in, const int* in_sizes, int n_in,
                              void* d_out, int out_size, void* d_ws, size_t ws_size,
                              hipStream_t stream) {
    const float* x = (const float*)d_in[0];
    const float* Wq = (const float*)d_in[1];
    const float* Wk = (const float*)d_in[2];
    const float* Wv = (const float*)d_in[3];
    float* out = (float*)d_out;

    char* ws = (char*)d_ws;
    size_t off = 0;
    auto alloc = [&](size_t elems) -> bf16* {
        bf16* p = (bf16*)(ws + off);
        off += elems * sizeof(bf16);
        return p;
    };
    bf16* xh = alloc((size_t)SEQ * EMB);
    bf16* xl = alloc((size_t)SEQ * EMB);
    bf16* wthq = alloc((size_t)EMB * EMB);
    bf16* wtlq = alloc((size_t)EMB * EMB);
    bf16* wthk = alloc((size_t)EMB * EMB);
    bf16* wtlk = alloc((size_t)EMB * EMB);
    bf16* wthv = alloc((size_t)EMB * EMB);
    bf16* wtlv = alloc((size_t)EMB * EMB);
    bf16* qh = alloc((size_t)SEQ * EMB);
    bf16* ql = alloc((size_t)SEQ * EMB);
    bf16* kh = alloc((size_t)SEQ * EMB);
    bf16* kl = alloc((size_t)SEQ * EMB);
    bf16* vt = alloc((size_t)SEQ * EMB);
    (void)ws_size; (void)in_sizes; (void)n_in; (void)out_size;

    split_kernel<<<(SEQ * EMB / 4 + 255) / 256, 256, 0, stream>>>(x, xh, xl, SEQ * EMB / 4);
    wtrans_kernel<<<dim3(32, 32, 3), dim3(32, 8), 0, stream>>>(
        Wq, Wk, Wv, wthq, wtlq, wthk, wtlk, wthv, wtlv);
    proj_qkv<<<dim3(24, 32), 256, 0, stream>>>(
        xh, xl, wthq, wtlq, wthk, wtlk, wthv, qh, ql, kh, kl, vt);
    attn_kernel<<<256, 512, 0, stream>>>(qh, ql, kh, kl, vt, out);
}